// Round 8
// baseline (614.100 us; speedup 1.0000x reference)
//
#include <hip/hip_runtime.h>
#include <hip/hip_bf16.h>

// Problem constants
#define NODES 379
#define NG    128
#define NN    48512          // NODES*NG
#define EE    1552384        // NN*32 ; divisible by 1024
#define EPAD2 (EE + 16 * NN) // CSR slots upper bound (8 subsegs pad2 + row pad8)
#define HID   128
#define INCH  379
#define KP1   384            // INCH padded to multiple of 64

typedef __bf16 bf16x8 __attribute__((ext_vector_type(8)));
typedef float  f32x4  __attribute__((ext_vector_type(4)));

__device__ __forceinline__ unsigned short f2bf(float f) {
    __hip_bfloat16 b = __float2bfloat16(f);
    return *reinterpret_cast<unsigned short*>(&b);
}
__device__ __forceinline__ float bflo(unsigned int g) {   // low bf16 -> f32
    return __uint_as_float(g << 16);
}
__device__ __forceinline__ float bfhi(unsigned int g) {   // high bf16 -> f32
    return __uint_as_float(g & 0xffff0000u);
}

// ---------------------------------------------------------------------------
// Edge hist: per-XCD-slot dst histogram. Block b covers edges [b*1024,+1024),
// uses private copy cnt8[b&7][*] so atomic lines stay XCD-local.
// ---------------------------------------------------------------------------
__global__ __launch_bounds__(256) void edge_hist8(
    const int* __restrict__ ei, int* __restrict__ cnt8)
{
    int b = blockIdx.x;
    int* cm = cnt8 + (size_t)(b & 7) * NN;
    int e0 = b * 1024 + threadIdx.x * 4;
    int4 d = *(const int4*)(ei + EE + e0);
    atomicAdd(&cm[d.x], 1);
    atomicAdd(&cm[d.y], 1);
    atomicAdd(&cm[d.z], 1);
    atomicAdd(&cm[d.w], 1);
}

// ---------------------------------------------------------------------------
// Scan: thread per row. Row n = 8 subsegs (one per XCD slot), each padded to
// 2 slots, row total padded to 8. Writes rowstart[n] (row begin; contiguous)
// and wpos8[x][n] (subseg begin, the scatter cursor).
// ---------------------------------------------------------------------------
__global__ __launch_bounds__(1024) void scan8_kernel(
    const int* __restrict__ cnt8, int* __restrict__ rowstart,
    int* __restrict__ wpos8)
{
    __shared__ int wsum[16];
    __shared__ int wpre[16];
    __shared__ int chunk_total;
    __shared__ int carry_s;
    int tid = threadIdx.x;
    int lane = tid & 63, wid = tid >> 6;
    if (tid == 0) carry_s = 0;
    __syncthreads();
    for (int base = 0; base < NN; base += 1024) {
        int n = base + tid;
        int c[8];
        int rowlen = 0;
        #pragma unroll
        for (int x = 0; x < 8; ++x) {
            int v = (n < NN) ? cnt8[(size_t)x * NN + n] : 0;
            c[x] = (v + 1) & ~1;              // pad subseg to multiple of 2
            rowlen += c[x];
        }
        rowlen = (rowlen + 7) & ~7;           // pad row to multiple of 8
        int incl = rowlen;
        #pragma unroll
        for (int off = 1; off < 64; off <<= 1) {
            int t = __shfl_up(incl, off);
            if (lane >= off) incl += t;
        }
        if (lane == 63) wsum[wid] = incl;
        __syncthreads();
        if (tid == 0) {
            int acc = 0;
            #pragma unroll
            for (int w = 0; w < 16; ++w) { wpre[w] = acc; acc += wsum[w]; }
            chunk_total = acc;
        }
        __syncthreads();
        int excl = carry_s + wpre[wid] + (incl - rowlen);
        if (n < NN) {
            rowstart[n] = excl;
            int off = excl;
            #pragma unroll
            for (int x = 0; x < 8; ++x) {
                wpos8[(size_t)x * NN + n] = off;
                off += c[x];
            }
        }
        __syncthreads();
        if (tid == 0) carry_s += chunk_total;
        __syncthreads();
    }
    if (tid == 0) rowstart[NN] = carry_s;
}

// ---------------------------------------------------------------------------
// Edge scatter: effective weight + scatter packed (src,w) into this block's
// XCD-slot subsegment of the dst row. Same edge->block mapping as edge_hist8.
// ---------------------------------------------------------------------------
__global__ __launch_bounds__(256) void edge_scatter(
    const int* __restrict__ ei, const float* __restrict__ ewt,
    const float* __restrict__ lew, int* __restrict__ wpos8,
    int2* __restrict__ edge_data)
{
    int b = blockIdx.x;
    int* wp = wpos8 + (size_t)(b & 7) * NN;
    int e0 = b * 1024 + threadIdx.x * 4;
    int4   s4 = *(const int4*)(ei + e0);
    int4   d4 = *(const int4*)(ei + EE + e0);
    float4 t4 = *(const float4*)(ewt + e0);
    // issue all 4 atomics first; compute sigmoid while they're in flight
    int p0 = atomicAdd(&wp[d4.x], 1);
    int p1 = atomicAdd(&wp[d4.y], 1);
    int p2 = atomicAdd(&wp[d4.z], 1);
    int p3 = atomicAdd(&wp[d4.w], 1);
    int srcs[4] = {s4.x, s4.y, s4.z, s4.w};
    int dsts[4] = {d4.x, d4.y, d4.z, d4.w};
    float ews[4] = {t4.x, t4.y, t4.z, t4.w};
    int pos[4] = {p0, p1, p2, p3};
    #pragma unroll
    for (int u = 0; u < 4; ++u) {
        int li = srcs[u] % NODES, lj = dsts[u] % NODES;
        float s = 0.5f * (lew[li * NODES + lj] + lew[lj * NODES + li]);
        float w = (2.0f / (1.0f + expf(-s))) * ews[u];
        edge_data[pos[u]] = make_int2(srcs[u], __float_as_int(w));
    }
}

// ---------------------------------------------------------------------------
// deg/dinv from CSR row sums (pads have w=0): dinv[n]=rsqrt(sum+1)
// ---------------------------------------------------------------------------
__global__ __launch_bounds__(256) void deg_from_csr(
    const int* __restrict__ rowstart, const int2* __restrict__ edge_data,
    float* __restrict__ dinv)
{
    int n = blockIdx.x * 256 + threadIdx.x;
    if (n >= NN) return;
    int e0 = rowstart[n], e1 = rowstart[n + 1];
    float s = 0.f;
    for (int e = e0; e < e1; e += 8) {
        int4 q0 = *(const int4*)(edge_data + e);
        int4 q1 = *(const int4*)(edge_data + e + 2);
        int4 q2 = *(const int4*)(edge_data + e + 4);
        int4 q3 = *(const int4*)(edge_data + e + 6);
        s += (__int_as_float(q0.y) + __int_as_float(q0.w))
           + (__int_as_float(q1.y) + __int_as_float(q1.w))
           + (__int_as_float(q2.y) + __int_as_float(q2.w))
           + (__int_as_float(q3.y) + __int_as_float(q3.w));
    }
    dinv[n] = rsqrtf(s + 1.0f);
}

// ---------------------------------------------------------------------------
// x[NN,379] f32 -> xb[NN,384] bf16 (zero-padded K)
// ---------------------------------------------------------------------------
__global__ __launch_bounds__(256) void convert_x(
    const float* __restrict__ x, unsigned short* __restrict__ xb)
{
    int idx = blockIdx.x * 256 + threadIdx.x;
    if (idx >= NN * 96) return;
    int r = idx / 96, kg = (idx % 96) * 4;
    const float* xp = x + (size_t)r * INCH + kg;
    ushort4 o;
    o.x = (kg + 0 < INCH) ? f2bf(xp[0]) : 0;
    o.y = (kg + 1 < INCH) ? f2bf(xp[1]) : 0;
    o.z = (kg + 2 < INCH) ? f2bf(xp[2]) : 0;
    o.w = (kg + 3 < INCH) ? f2bf(xp[3]) : 0;
    *(ushort4*)(xb + (size_t)r * KP1 + kg) = o;
}

// ---------------------------------------------------------------------------
// Weights: WcatT[256][384] bf16 (row n: col n of [W1|We], K zero-padded),
//          W2T[128][128] bf16 (row n: col n of W2)
// ---------------------------------------------------------------------------
__global__ __launch_bounds__(256) void build_wt(
    const float* __restrict__ W1, const float* __restrict__ We,
    const float* __restrict__ W2,
    unsigned short* __restrict__ WcatT, unsigned short* __restrict__ W2T)
{
    int idx = blockIdx.x * 256 + threadIdx.x;
    if (idx < 256 * KP1) {
        int n = idx / KP1, k = idx % KP1;
        float v = 0.f;
        if (k < INCH) v = (n < 128) ? W1[k * 128 + n] : We[k * 128 + (n - 128)];
        WcatT[idx] = f2bf(v);
    } else {
        int i2 = idx - 256 * KP1;
        if (i2 < 128 * 128) {
            int n = i2 / 128, k = i2 % 128;
            W2T[i2] = f2bf(W2[k * 128 + n]);
        }
    }
}

// ---------------------------------------------------------------------------
// bf16 MFMA GEMM: C = A[M,Kp] @ WT[N,Kp]^T, output bf16.
// 128x128 tile, BK=64, 256 thr = 4 waves (2x2 of 64x64 each).
// LDS rows 128 B -> XOR swizzle byte^=(row&7)<<4 on write AND read (G4).
// Output cols 0..127 -> C0 (scaled by dscale[row]), 128..255 -> C1 (unscaled).
// ---------------------------------------------------------------------------
__global__ __launch_bounds__(256) void mfma_gemm(
    const unsigned short* __restrict__ A, int lda,
    const unsigned short* __restrict__ WT, int ldw,
    unsigned short* __restrict__ C0, unsigned short* __restrict__ C1,
    const float* __restrict__ dscale, int Kp)
{
    __shared__ char lds[32 * 1024];
    char* lA = lds;
    char* lB = lds + 16 * 1024;
    int tid = threadIdx.x;
    int lane = tid & 63, wid = tid >> 6;
    int wr = wid >> 1, wc = wid & 1;
    int l16 = lane & 15, lq = lane >> 4;
    size_t bm = (size_t)blockIdx.x * 128;
    int bn = blockIdx.y * 128;
    f32x4 acc[4][4] = {};

    for (int kb = 0; kb < Kp; kb += 64) {
        {   // stage A tile [128 rows][64 k] and B tile [128 cols][64 k]
            int r = tid >> 1, hk = tid & 1;
            const char* ga = (const char*)(A + (bm + r) * (size_t)lda + kb + hk * 32);
            const char* gb = (const char*)(WT + (size_t)(bn + r) * ldw + kb + hk * 32);
            int rs = (r & 7) << 4;
            #pragma unroll
            for (int i = 0; i < 4; ++i) {
                int4 va = *(const int4*)(ga + i * 16);
                *(int4*)(lA + ((r * 128 + hk * 64 + i * 16) ^ rs)) = va;
            }
            #pragma unroll
            for (int i = 0; i < 4; ++i) {
                int4 vb = *(const int4*)(gb + i * 16);
                *(int4*)(lB + ((r * 128 + hk * 64 + i * 16) ^ rs)) = vb;
            }
        }
        __syncthreads();
        #pragma unroll
        for (int ks = 0; ks < 2; ++ks) {
            int kbyte = ks * 64 + lq * 16;
            bf16x8 af[4], bfr[4];
            #pragma unroll
            for (int mi = 0; mi < 4; ++mi) {
                int r = wr * 64 + mi * 16 + l16;
                af[mi] = *(const bf16x8*)(lA + ((r * 128 + kbyte) ^ ((r & 7) << 4)));
            }
            #pragma unroll
            for (int ni = 0; ni < 4; ++ni) {
                int c = wc * 64 + ni * 16 + l16;
                bfr[ni] = *(const bf16x8*)(lB + ((c * 128 + kbyte) ^ ((c & 7) << 4)));
            }
            #pragma unroll
            for (int mi = 0; mi < 4; ++mi)
                #pragma unroll
                for (int ni = 0; ni < 4; ++ni)
                    acc[mi][ni] = __builtin_amdgcn_mfma_f32_16x16x32_bf16(
                        af[mi], bfr[ni], acc[mi][ni], 0, 0, 0);
        }
        __syncthreads();
    }
    // epilogue: C/D layout col=lane&15, row=(lane>>4)*4+reg
    #pragma unroll
    for (int mi = 0; mi < 4; ++mi) {
        size_t rowbase = bm + wr * 64 + mi * 16 + lq * 4;
        float dsc[4];
        #pragma unroll
        for (int j = 0; j < 4; ++j) dsc[j] = dscale[rowbase + j];
        #pragma unroll
        for (int ni = 0; ni < 4; ++ni) {
            int col = bn + wc * 64 + ni * 16 + l16;
            bool toC0 = (col < 128);
            unsigned short* Cb = toC0 ? C0 : C1;
            int cc = toC0 ? col : (col - 128);
            #pragma unroll
            for (int j = 0; j < 4; ++j) {
                float v = acc[mi][ni][j];
                if (toC0) v *= dsc[j];
                Cb[(rowbase + j) * 128 + cc] = f2bf(v);
            }
        }
    }
}

// ---------------------------------------------------------------------------
// Aggregation v5: 1 wave per node (2 nodes per 128-thread block).
// Lane owns 2 adjacent columns via one uint (2xbf16) gather per edge.
// Edge meta = packed int2 (src, w) -> int4 loads give 2 edges.
// Tables pre-scaled by dinv: conv[n] = dinv[n]*(sum ew*T[src] + T[n]) + b
// ---------------------------------------------------------------------------
#define AGG_GATHER(q, gA, gB, wA, wB, TBL)                                    \
    {                                                                         \
        gA = *(const unsigned int*)(TBL + (size_t)(q).x * 128 + co);          \
        gB = *(const unsigned int*)(TBL + (size_t)(q).z * 128 + co);          \
        wA = __int_as_float((q).y);                                           \
        wB = __int_as_float((q).w);                                           \
    }

__global__ __launch_bounds__(128) void aggregate1_v5(
    const unsigned short* __restrict__ t1, const unsigned short* __restrict__ xeb,
    const int* __restrict__ rowstart, const int2* __restrict__ edge_data,
    const float* __restrict__ dinv, const float* __restrict__ b1,
    const float* __restrict__ be, unsigned short* __restrict__ hb)
{
    int lane = threadIdx.x & 63;
    int n = blockIdx.x * 2 + (threadIdx.x >> 6);
    int co = lane << 1;
    int e0 = rowstart[n], e1 = rowstart[n + 1];
    float aL = 0.f, aH = 0.f;
    for (int e = e0; e < e1; e += 8) {
        int4 q0 = *(const int4*)(edge_data + e);
        int4 q1 = *(const int4*)(edge_data + e + 2);
        int4 q2 = *(const int4*)(edge_data + e + 4);
        int4 q3 = *(const int4*)(edge_data + e + 6);
        unsigned int g0, g1, g2, g3, g4, g5, g6, g7;
        float w0, w1, w2, w3, w4, w5, w6, w7;
        AGG_GATHER(q0, g0, g1, w0, w1, t1);
        AGG_GATHER(q1, g2, g3, w2, w3, t1);
        AGG_GATHER(q2, g4, g5, w4, w5, t1);
        AGG_GATHER(q3, g6, g7, w6, w7, t1);
        aL = fmaf(w0, bflo(g0), aL); aH = fmaf(w0, bfhi(g0), aH);
        aL = fmaf(w1, bflo(g1), aL); aH = fmaf(w1, bfhi(g1), aH);
        aL = fmaf(w2, bflo(g2), aL); aH = fmaf(w2, bfhi(g2), aH);
        aL = fmaf(w3, bflo(g3), aL); aH = fmaf(w3, bfhi(g3), aH);
        aL = fmaf(w4, bflo(g4), aL); aH = fmaf(w4, bfhi(g4), aH);
        aL = fmaf(w5, bflo(g5), aL); aH = fmaf(w5, bfhi(g5), aH);
        aL = fmaf(w6, bflo(g6), aL); aH = fmaf(w6, bfhi(g6), aH);
        aL = fmaf(w7, bflo(g7), aL); aH = fmaf(w7, bfhi(g7), aH);
    }
    unsigned int tn  = *(const unsigned int*)(t1 + (size_t)n * 128 + co);
    unsigned int xen = *(const unsigned int*)(xeb + (size_t)n * 128 + co);
    float d = dinv[n];
    float2 bb1 = *(const float2*)(b1 + co);
    float2 bbe = *(const float2*)(be + co);
    float oL = fmaxf(fmaf(d, aL + bflo(tn), bb1.x), 0.f)
             + fmaxf(bflo(xen) + bbe.x, 0.f);
    float oH = fmaxf(fmaf(d, aH + bfhi(tn), bb1.y), 0.f)
             + fmaxf(bfhi(xen) + bbe.y, 0.f);
    unsigned int packed = (unsigned int)f2bf(oL) | ((unsigned int)f2bf(oH) << 16);
    *(unsigned int*)(hb + (size_t)n * 128 + co) = packed;
}

__global__ __launch_bounds__(128) void aggregate2_v5(
    const unsigned short* __restrict__ t2, const int* __restrict__ rowstart,
    const int2* __restrict__ edge_data,
    const float* __restrict__ dinv, const float* __restrict__ b2,
    const unsigned short* __restrict__ hb, unsigned short* __restrict__ out_buf)
{
    int lane = threadIdx.x & 63;
    int n = blockIdx.x * 2 + (threadIdx.x >> 6);
    int co = lane << 1;
    int e0 = rowstart[n], e1 = rowstart[n + 1];
    float aL = 0.f, aH = 0.f;
    for (int e = e0; e < e1; e += 8) {
        int4 q0 = *(const int4*)(edge_data + e);
        int4 q1 = *(const int4*)(edge_data + e + 2);
        int4 q2 = *(const int4*)(edge_data + e + 4);
        int4 q3 = *(const int4*)(edge_data + e + 6);
        unsigned int g0, g1, g2, g3, g4, g5, g6, g7;
        float w0, w1, w2, w3, w4, w5, w6, w7;
        AGG_GATHER(q0, g0, g1, w0, w1, t2);
        AGG_GATHER(q1, g2, g3, w2, w3, t2);
        AGG_GATHER(q2, g4, g5, w4, w5, t2);
        AGG_GATHER(q3, g6, g7, w6, w7, t2);
        aL = fmaf(w0, bflo(g0), aL); aH = fmaf(w0, bfhi(g0), aH);
        aL = fmaf(w1, bflo(g1), aL); aH = fmaf(w1, bfhi(g1), aH);
        aL = fmaf(w2, bflo(g2), aL); aH = fmaf(w2, bfhi(g2), aH);
        aL = fmaf(w3, bflo(g3), aL); aH = fmaf(w3, bfhi(g3), aH);
        aL = fmaf(w4, bflo(g4), aL); aH = fmaf(w4, bfhi(g4), aH);
        aL = fmaf(w5, bflo(g5), aL); aH = fmaf(w5, bfhi(g5), aH);
        aL = fmaf(w6, bflo(g6), aL); aH = fmaf(w6, bfhi(g6), aH);
        aL = fmaf(w7, bflo(g7), aL); aH = fmaf(w7, bfhi(g7), aH);
    }
    unsigned int tn = *(const unsigned int*)(t2 + (size_t)n * 128 + co);
    unsigned int hr = *(const unsigned int*)(hb + (size_t)n * 128 + co);
    float d = dinv[n];
    float2 bb2 = *(const float2*)(b2 + co);
    float oL = fmaxf(fmaf(d, aL + bflo(tn), bb2.x), 0.f) + bflo(hr);
    float oH = fmaxf(fmaf(d, aH + bfhi(tn), bb2.y), 0.f) + bfhi(hr);
    unsigned int packed = (unsigned int)f2bf(oL) | ((unsigned int)f2bf(oH) << 16);
    *(unsigned int*)(out_buf + (size_t)n * 128 + co) = packed;
}

// ---------------------------------------------------------------------------
// pool + FC fused: out[g] = (1/379)*sum_{i,c} out_buf[g*379+i, c]*Wfc[c] + bfc
// 512 threads: lane covers 2 cols (one uint), 8 row groups
// ---------------------------------------------------------------------------
__global__ __launch_bounds__(512) void pool_fc(
    const unsigned short* __restrict__ out_buf, const float* __restrict__ Wfc,
    const float* __restrict__ bfc, float* __restrict__ out)
{
    int g = blockIdx.x;
    int t = threadIdx.x;
    int c2 = (t & 63) * 2, q = t >> 6;
    const unsigned short* p = out_buf + ((size_t)g * NODES + q) * 128 + c2;
    float sL = 0.f, sH = 0.f;
    for (int i = q; i < NODES; i += 8) {
        unsigned int v = *(const unsigned int*)p;
        sL += bflo(v);
        sH += bfhi(v);
        p += 8 * 128;
    }
    float v = sL * Wfc[c2] + sH * Wfc[c2 + 1];
    #pragma unroll
    for (int off = 32; off > 0; off >>= 1) v += __shfl_down(v, off);
    __shared__ float ws8[8];
    if ((t & 63) == 0) ws8[t >> 6] = v;
    __syncthreads();
    if (t == 0) {
        float tot = 0.f;
        #pragma unroll
        for (int k = 0; k < 8; ++k) tot += ws8[k];
        out[g] = tot * (1.0f / (float)NODES) + bfc[0];
    }
}

// ---------------------------------------------------------------------------
extern "C" void kernel_launch(void* const* d_in, const int* in_sizes, int n_in,
                              void* d_out, int out_size, void* d_ws, size_t ws_size,
                              hipStream_t stream)
{
    const float* x   = (const float*)d_in[0];
    const int*   ei  = (const int*)d_in[1];
    const float* ewt = (const float*)d_in[2];
    // d_in[3] = batch (unused; batch[n] == n/379)
    const float* lew = (const float*)d_in[4];
    const float* W1  = (const float*)d_in[5];
    const float* b1  = (const float*)d_in[6];
    const float* W2  = (const float*)d_in[7];
    const float* b2  = (const float*)d_in[8];
    const float* We  = (const float*)d_in[9];
    const float* be  = (const float*)d_in[10];
    const float* Wfc = (const float*)d_in[11];
    const float* bfc = (const float*)d_in[12];
    float* outp = (float*)d_out;

    // workspace layout
    char* p = (char*)d_ws;
    auto alloc = [&](size_t bytes) { void* r = (void*)p; p += (bytes + 255) & ~(size_t)255; return r; };
    int2*  edge_data  = (int2*)alloc((size_t)EPAD2 * 8);
    int*   cnt8       = (int*)alloc((size_t)8 * NN * 4);
    int*   wpos8      = (int*)alloc((size_t)8 * NN * 4);
    int*   rowstart   = (int*)alloc((size_t)(NN + 1) * 4);
    float* dinv       = (float*)alloc((size_t)NN * 4);
    unsigned short* WcatT = (unsigned short*)alloc((size_t)256 * KP1 * 2);
    unsigned short* W2T   = (unsigned short*)alloc((size_t)128 * 128 * 2);
    unsigned short* xb    = (unsigned short*)alloc((size_t)NN * KP1 * 2);
    unsigned short* xw1b  = (unsigned short*)alloc((size_t)NN * HID * 2);
    unsigned short* xeb   = (unsigned short*)alloc((size_t)NN * HID * 2);
    unsigned short* hw2b  = (unsigned short*)alloc((size_t)NN * HID * 2);
    unsigned short* out_buf = (unsigned short*)alloc((size_t)NN * HID * 2);
    // alias (disjoint live ranges): xb dead after GEMM1; hb born in aggregate1
    unsigned short* hb = xb;

    // zero histogram + padded CSR (ws is poisoned 0xAA before every launch)
    hipMemsetAsync(cnt8, 0, (size_t)8 * NN * 4, stream);
    hipMemsetAsync(edge_data, 0, (size_t)EPAD2 * 8, stream);

    const int NB = (NN + 255) / 256;     // 190
    const int EB1024 = EE / 1024;        // 1516

    convert_x<<<(NN * 96 + 255) / 256, 256, 0, stream>>>(x, xb);
    build_wt<<<(256 * KP1 + 128 * 128 + 255) / 256, 256, 0, stream>>>(W1, We, W2, WcatT, W2T);

    edge_hist8<<<EB1024, 256, 0, stream>>>(ei, cnt8);
    scan8_kernel<<<1, 1024, 0, stream>>>(cnt8, rowstart, wpos8);
    edge_scatter<<<EB1024, 256, 0, stream>>>(ei, ewt, lew, wpos8, edge_data);
    deg_from_csr<<<NB, 256, 0, stream>>>(rowstart, edge_data, dinv);

    // GEMM1: xw1b = dinv*(xb@W1) bf16 ; xeb = xb@We bf16
    {
        dim3 grid(NN / 128, 2);
        mfma_gemm<<<grid, 256, 0, stream>>>(xb, KP1, WcatT, KP1, xw1b, xeb, dinv, KP1);
    }
    aggregate1_v5<<<NN / 2, 128, 0, stream>>>(xw1b, xeb, rowstart, edge_data,
                                              dinv, b1, be, hb);
    // GEMM2: hw2b = dinv*(hb@W2) bf16
    {
        dim3 grid(NN / 128, 1);
        mfma_gemm<<<grid, 256, 0, stream>>>(hb, 128, W2T, 128, hw2b, nullptr, dinv, 128);
    }
    aggregate2_v5<<<NN / 2, 128, 0, stream>>>(hw2b, rowstart, edge_data,
                                              dinv, b2, hb, out_buf);
    pool_fc<<<NG, 512, 0, stream>>>(out_buf, Wfc, bfc, outp);
}

// Round 9
// 462.719 us; speedup vs baseline: 1.3272x; 1.3272x over previous
//
#include <hip/hip_runtime.h>
#include <hip/hip_bf16.h>

// Problem constants
#define NODES 379
#define NG    128
#define NN    48512          // NODES*NG
#define EE    1552384        // NN*32 ; divisible by 1024
#define EPAD2 (EE + 16 * NN) // CSR slots upper bound (8 subsegs pad2 + row pad8)
#define HID   128
#define INCH  379
#define KP1   384            // INCH padded to multiple of 64
#define NBLK  ((NN + 255) / 256)   // 190 blocks for row-parallel kernels

typedef __bf16 bf16x8 __attribute__((ext_vector_type(8)));
typedef float  f32x4  __attribute__((ext_vector_type(4)));

__device__ __forceinline__ unsigned short f2bf(float f) {
    __hip_bfloat16 b = __float2bfloat16(f);
    return *reinterpret_cast<unsigned short*>(&b);
}
__device__ __forceinline__ float bflo(unsigned int g) {   // low bf16 -> f32
    return __uint_as_float(g << 16);
}
__device__ __forceinline__ float bfhi(unsigned int g) {   // high bf16 -> f32
    return __uint_as_float(g & 0xffff0000u);
}

// ---------------------------------------------------------------------------
// Edge hist: per-XCD-slot dst histogram. Block b covers edges [b*1024,+1024),
// uses private copy cnt8[b&7][*] so atomic lines stay XCD-local.
// ---------------------------------------------------------------------------
__global__ __launch_bounds__(256) void edge_hist8(
    const int* __restrict__ ei, int* __restrict__ cnt8)
{
    int b = blockIdx.x;
    int* cm = cnt8 + (size_t)(b & 7) * NN;
    int e0 = b * 1024 + threadIdx.x * 4;
    int4 d = *(const int4*)(ei + EE + e0);
    atomicAdd(&cm[d.x], 1);
    atomicAdd(&cm[d.y], 1);
    atomicAdd(&cm[d.z], 1);
    atomicAdd(&cm[d.w], 1);
}

// ---------------------------------------------------------------------------
// Parallel 3-phase scan over padded row lengths.
// Row n = 8 subsegs (per XCD slot), each padded to mult of 2; row padded to 8.
// ---------------------------------------------------------------------------
__device__ __forceinline__ int row_len8(const int* cnt8, int n, int* c)
{
    int rowlen = 0;
    #pragma unroll
    for (int x = 0; x < 8; ++x) {
        int v = (n < NN) ? cnt8[(size_t)x * NN + n] : 0;
        c[x] = (v + 1) & ~1;
        rowlen += c[x];
    }
    return (rowlen + 7) & ~7;
}

// Phase 1: per-block sum of row lengths
__global__ __launch_bounds__(256) void scan_rows(
    const int* __restrict__ cnt8, int* __restrict__ blocksum)
{
    int n = blockIdx.x * 256 + threadIdx.x;
    int c[8];
    int rowlen = row_len8(cnt8, n, c);
    // wave reduce then cross-wave
    #pragma unroll
    for (int off = 32; off > 0; off >>= 1) rowlen += __shfl_down(rowlen, off);
    __shared__ int ws[4];
    if ((threadIdx.x & 63) == 0) ws[threadIdx.x >> 6] = rowlen;
    __syncthreads();
    if (threadIdx.x == 0)
        blocksum[blockIdx.x] = ws[0] + ws[1] + ws[2] + ws[3];
}

// Phase 2: exclusive scan of NBLK block sums (single 256-thread block)
__global__ __launch_bounds__(256) void scan_blocks(
    const int* __restrict__ blocksum, int* __restrict__ blockoff,
    int* __restrict__ rowstart)
{
    int tid = threadIdx.x;
    int lane = tid & 63, wid = tid >> 6;
    int v = (tid < NBLK) ? blocksum[tid] : 0;
    int incl = v;
    #pragma unroll
    for (int off = 1; off < 64; off <<= 1) {
        int t = __shfl_up(incl, off);
        if (lane >= off) incl += t;
    }
    __shared__ int wsum[4], wpre[4];
    if (lane == 63) wsum[wid] = incl;
    __syncthreads();
    if (tid == 0) {
        int acc = 0;
        #pragma unroll
        for (int w = 0; w < 4; ++w) { wpre[w] = acc; acc += wsum[w]; }
        rowstart[NN] = acc;               // grand total
    }
    __syncthreads();
    if (tid < NBLK) blockoff[tid] = wpre[wid] + incl - v;
}

// Phase 3: block-wide scan + write rowstart and the 8 wpos cursors
__global__ __launch_bounds__(256) void scan_write(
    const int* __restrict__ cnt8, const int* __restrict__ blockoff,
    int* __restrict__ rowstart, int* __restrict__ wpos8)
{
    int tid = threadIdx.x;
    int lane = tid & 63, wid = tid >> 6;
    int n = blockIdx.x * 256 + tid;
    int c[8];
    int rowlen = row_len8(cnt8, n, c);
    int incl = rowlen;
    #pragma unroll
    for (int off = 1; off < 64; off <<= 1) {
        int t = __shfl_up(incl, off);
        if (lane >= off) incl += t;
    }
    __shared__ int wsum[4], wpre[4];
    if (lane == 63) wsum[wid] = incl;
    __syncthreads();
    if (tid == 0) {
        int acc = 0;
        #pragma unroll
        for (int w = 0; w < 4; ++w) { wpre[w] = acc; acc += wsum[w]; }
    }
    __syncthreads();
    if (n < NN) {
        int excl = blockoff[blockIdx.x] + wpre[wid] + incl - rowlen;
        rowstart[n] = excl;
        int off = excl;
        #pragma unroll
        for (int x = 0; x < 8; ++x) {
            wpos8[(size_t)x * NN + n] = off;
            off += c[x];
        }
    }
}

// ---------------------------------------------------------------------------
// Edge scatter: effective weight + scatter packed (src,w) into this block's
// XCD-slot subsegment of the dst row. Same edge->block mapping as edge_hist8.
// ---------------------------------------------------------------------------
__global__ __launch_bounds__(256) void edge_scatter(
    const int* __restrict__ ei, const float* __restrict__ ewt,
    const float* __restrict__ lew, int* __restrict__ wpos8,
    int2* __restrict__ edge_data)
{
    int b = blockIdx.x;
    int* wp = wpos8 + (size_t)(b & 7) * NN;
    int e0 = b * 1024 + threadIdx.x * 4;
    int4   s4 = *(const int4*)(ei + e0);
    int4   d4 = *(const int4*)(ei + EE + e0);
    float4 t4 = *(const float4*)(ewt + e0);
    // issue all 4 atomics first; compute sigmoid while they're in flight
    int p0 = atomicAdd(&wp[d4.x], 1);
    int p1 = atomicAdd(&wp[d4.y], 1);
    int p2 = atomicAdd(&wp[d4.z], 1);
    int p3 = atomicAdd(&wp[d4.w], 1);
    int srcs[4] = {s4.x, s4.y, s4.z, s4.w};
    int dsts[4] = {d4.x, d4.y, d4.z, d4.w};
    float ews[4] = {t4.x, t4.y, t4.z, t4.w};
    int pos[4] = {p0, p1, p2, p3};
    #pragma unroll
    for (int u = 0; u < 4; ++u) {
        int li = srcs[u] % NODES, lj = dsts[u] % NODES;
        float s = 0.5f * (lew[li * NODES + lj] + lew[lj * NODES + li]);
        float w = (2.0f / (1.0f + expf(-s))) * ews[u];
        edge_data[pos[u]] = make_int2(srcs[u], __float_as_int(w));
    }
}

// ---------------------------------------------------------------------------
// deg/dinv from CSR row sums (pads have w=0): dinv[n]=rsqrt(sum+1)
// ---------------------------------------------------------------------------
__global__ __launch_bounds__(256) void deg_from_csr(
    const int* __restrict__ rowstart, const int2* __restrict__ edge_data,
    float* __restrict__ dinv)
{
    int n = blockIdx.x * 256 + threadIdx.x;
    if (n >= NN) return;
    int e0 = rowstart[n], e1 = rowstart[n + 1];
    float s = 0.f;
    for (int e = e0; e < e1; e += 8) {
        int4 q0 = *(const int4*)(edge_data + e);
        int4 q1 = *(const int4*)(edge_data + e + 2);
        int4 q2 = *(const int4*)(edge_data + e + 4);
        int4 q3 = *(const int4*)(edge_data + e + 6);
        s += (__int_as_float(q0.y) + __int_as_float(q0.w))
           + (__int_as_float(q1.y) + __int_as_float(q1.w))
           + (__int_as_float(q2.y) + __int_as_float(q2.w))
           + (__int_as_float(q3.y) + __int_as_float(q3.w));
    }
    dinv[n] = rsqrtf(s + 1.0f);
}

// ---------------------------------------------------------------------------
// x[NN,379] f32 -> xb[NN,384] bf16 (zero-padded K)
// ---------------------------------------------------------------------------
__global__ __launch_bounds__(256) void convert_x(
    const float* __restrict__ x, unsigned short* __restrict__ xb)
{
    int idx = blockIdx.x * 256 + threadIdx.x;
    if (idx >= NN * 96) return;
    int r = idx / 96, kg = (idx % 96) * 4;
    const float* xp = x + (size_t)r * INCH + kg;
    ushort4 o;
    o.x = (kg + 0 < INCH) ? f2bf(xp[0]) : 0;
    o.y = (kg + 1 < INCH) ? f2bf(xp[1]) : 0;
    o.z = (kg + 2 < INCH) ? f2bf(xp[2]) : 0;
    o.w = (kg + 3 < INCH) ? f2bf(xp[3]) : 0;
    *(ushort4*)(xb + (size_t)r * KP1 + kg) = o;
}

// ---------------------------------------------------------------------------
// Weights: WcatT[256][384] bf16 (row n: col n of [W1|We], K zero-padded),
//          W2T[128][128] bf16 (row n: col n of W2)
// ---------------------------------------------------------------------------
__global__ __launch_bounds__(256) void build_wt(
    const float* __restrict__ W1, const float* __restrict__ We,
    const float* __restrict__ W2,
    unsigned short* __restrict__ WcatT, unsigned short* __restrict__ W2T)
{
    int idx = blockIdx.x * 256 + threadIdx.x;
    if (idx < 256 * KP1) {
        int n = idx / KP1, k = idx % KP1;
        float v = 0.f;
        if (k < INCH) v = (n < 128) ? W1[k * 128 + n] : We[k * 128 + (n - 128)];
        WcatT[idx] = f2bf(v);
    } else {
        int i2 = idx - 256 * KP1;
        if (i2 < 128 * 128) {
            int n = i2 / 128, k = i2 % 128;
            W2T[i2] = f2bf(W2[k * 128 + n]);
        }
    }
}

// ---------------------------------------------------------------------------
// bf16 MFMA GEMM: C = A[M,Kp] @ WT[N,Kp]^T, output bf16.
// 128x128 tile, BK=64, 256 thr = 4 waves (2x2 of 64x64 each).
// LDS rows 128 B -> XOR swizzle byte^=(row&7)<<4 on write AND read (G4).
// Output cols 0..127 -> C0 (scaled by dscale[row]), 128..255 -> C1 (unscaled).
// ---------------------------------------------------------------------------
__global__ __launch_bounds__(256) void mfma_gemm(
    const unsigned short* __restrict__ A, int lda,
    const unsigned short* __restrict__ WT, int ldw,
    unsigned short* __restrict__ C0, unsigned short* __restrict__ C1,
    const float* __restrict__ dscale, int Kp)
{
    __shared__ char lds[32 * 1024];
    char* lA = lds;
    char* lB = lds + 16 * 1024;
    int tid = threadIdx.x;
    int lane = tid & 63, wid = tid >> 6;
    int wr = wid >> 1, wc = wid & 1;
    int l16 = lane & 15, lq = lane >> 4;
    size_t bm = (size_t)blockIdx.x * 128;
    int bn = blockIdx.y * 128;
    f32x4 acc[4][4] = {};

    for (int kb = 0; kb < Kp; kb += 64) {
        {   // stage A tile [128 rows][64 k] and B tile [128 cols][64 k]
            int r = tid >> 1, hk = tid & 1;
            const char* ga = (const char*)(A + (bm + r) * (size_t)lda + kb + hk * 32);
            const char* gb = (const char*)(WT + (size_t)(bn + r) * ldw + kb + hk * 32);
            int rs = (r & 7) << 4;
            #pragma unroll
            for (int i = 0; i < 4; ++i) {
                int4 va = *(const int4*)(ga + i * 16);
                *(int4*)(lA + ((r * 128 + hk * 64 + i * 16) ^ rs)) = va;
            }
            #pragma unroll
            for (int i = 0; i < 4; ++i) {
                int4 vb = *(const int4*)(gb + i * 16);
                *(int4*)(lB + ((r * 128 + hk * 64 + i * 16) ^ rs)) = vb;
            }
        }
        __syncthreads();
        #pragma unroll
        for (int ks = 0; ks < 2; ++ks) {
            int kbyte = ks * 64 + lq * 16;
            bf16x8 af[4], bfr[4];
            #pragma unroll
            for (int mi = 0; mi < 4; ++mi) {
                int r = wr * 64 + mi * 16 + l16;
                af[mi] = *(const bf16x8*)(lA + ((r * 128 + kbyte) ^ ((r & 7) << 4)));
            }
            #pragma unroll
            for (int ni = 0; ni < 4; ++ni) {
                int c = wc * 64 + ni * 16 + l16;
                bfr[ni] = *(const bf16x8*)(lB + ((c * 128 + kbyte) ^ ((c & 7) << 4)));
            }
            #pragma unroll
            for (int mi = 0; mi < 4; ++mi)
                #pragma unroll
                for (int ni = 0; ni < 4; ++ni)
                    acc[mi][ni] = __builtin_amdgcn_mfma_f32_16x16x32_bf16(
                        af[mi], bfr[ni], acc[mi][ni], 0, 0, 0);
        }
        __syncthreads();
    }
    // epilogue: C/D layout col=lane&15, row=(lane>>4)*4+reg
    #pragma unroll
    for (int mi = 0; mi < 4; ++mi) {
        size_t rowbase = bm + wr * 64 + mi * 16 + lq * 4;
        float dsc[4];
        #pragma unroll
        for (int j = 0; j < 4; ++j) dsc[j] = dscale[rowbase + j];
        #pragma unroll
        for (int ni = 0; ni < 4; ++ni) {
            int col = bn + wc * 64 + ni * 16 + l16;
            bool toC0 = (col < 128);
            unsigned short* Cb = toC0 ? C0 : C1;
            int cc = toC0 ? col : (col - 128);
            #pragma unroll
            for (int j = 0; j < 4; ++j) {
                float v = acc[mi][ni][j];
                if (toC0) v *= dsc[j];
                Cb[(rowbase + j) * 128 + cc] = f2bf(v);
            }
        }
    }
}

// ---------------------------------------------------------------------------
// Aggregation v5: 1 wave per node (2 nodes per 128-thread block).
// Lane owns 2 adjacent columns via one uint (2xbf16) gather per edge.
// Edge meta = packed int2 (src, w) -> int4 loads give 2 edges.
// Tables pre-scaled by dinv: conv[n] = dinv[n]*(sum ew*T[src] + T[n]) + b
// ---------------------------------------------------------------------------
#define AGG_GATHER(q, gA, gB, wA, wB, TBL)                                    \
    {                                                                         \
        gA = *(const unsigned int*)(TBL + (size_t)(q).x * 128 + co);          \
        gB = *(const unsigned int*)(TBL + (size_t)(q).z * 128 + co);          \
        wA = __int_as_float((q).y);                                           \
        wB = __int_as_float((q).w);                                           \
    }

__global__ __launch_bounds__(128) void aggregate1_v5(
    const unsigned short* __restrict__ t1, const unsigned short* __restrict__ xeb,
    const int* __restrict__ rowstart, const int2* __restrict__ edge_data,
    const float* __restrict__ dinv, const float* __restrict__ b1,
    const float* __restrict__ be, unsigned short* __restrict__ hb)
{
    int lane = threadIdx.x & 63;
    int n = blockIdx.x * 2 + (threadIdx.x >> 6);
    int co = lane << 1;
    int e0 = rowstart[n], e1 = rowstart[n + 1];
    float aL = 0.f, aH = 0.f;
    for (int e = e0; e < e1; e += 8) {
        int4 q0 = *(const int4*)(edge_data + e);
        int4 q1 = *(const int4*)(edge_data + e + 2);
        int4 q2 = *(const int4*)(edge_data + e + 4);
        int4 q3 = *(const int4*)(edge_data + e + 6);
        unsigned int g0, g1, g2, g3, g4, g5, g6, g7;
        float w0, w1, w2, w3, w4, w5, w6, w7;
        AGG_GATHER(q0, g0, g1, w0, w1, t1);
        AGG_GATHER(q1, g2, g3, w2, w3, t1);
        AGG_GATHER(q2, g4, g5, w4, w5, t1);
        AGG_GATHER(q3, g6, g7, w6, w7, t1);
        aL = fmaf(w0, bflo(g0), aL); aH = fmaf(w0, bfhi(g0), aH);
        aL = fmaf(w1, bflo(g1), aL); aH = fmaf(w1, bfhi(g1), aH);
        aL = fmaf(w2, bflo(g2), aL); aH = fmaf(w2, bfhi(g2), aH);
        aL = fmaf(w3, bflo(g3), aL); aH = fmaf(w3, bfhi(g3), aH);
        aL = fmaf(w4, bflo(g4), aL); aH = fmaf(w4, bfhi(g4), aH);
        aL = fmaf(w5, bflo(g5), aL); aH = fmaf(w5, bfhi(g5), aH);
        aL = fmaf(w6, bflo(g6), aL); aH = fmaf(w6, bfhi(g6), aH);
        aL = fmaf(w7, bflo(g7), aL); aH = fmaf(w7, bfhi(g7), aH);
    }
    unsigned int tn  = *(const unsigned int*)(t1 + (size_t)n * 128 + co);
    unsigned int xen = *(const unsigned int*)(xeb + (size_t)n * 128 + co);
    float d = dinv[n];
    float2 bb1 = *(const float2*)(b1 + co);
    float2 bbe = *(const float2*)(be + co);
    float oL = fmaxf(fmaf(d, aL + bflo(tn), bb1.x), 0.f)
             + fmaxf(bflo(xen) + bbe.x, 0.f);
    float oH = fmaxf(fmaf(d, aH + bfhi(tn), bb1.y), 0.f)
             + fmaxf(bfhi(xen) + bbe.y, 0.f);
    unsigned int packed = (unsigned int)f2bf(oL) | ((unsigned int)f2bf(oH) << 16);
    *(unsigned int*)(hb + (size_t)n * 128 + co) = packed;
}

__global__ __launch_bounds__(128) void aggregate2_v5(
    const unsigned short* __restrict__ t2, const int* __restrict__ rowstart,
    const int2* __restrict__ edge_data,
    const float* __restrict__ dinv, const float* __restrict__ b2,
    const unsigned short* __restrict__ hb, unsigned short* __restrict__ out_buf)
{
    int lane = threadIdx.x & 63;
    int n = blockIdx.x * 2 + (threadIdx.x >> 6);
    int co = lane << 1;
    int e0 = rowstart[n], e1 = rowstart[n + 1];
    float aL = 0.f, aH = 0.f;
    for (int e = e0; e < e1; e += 8) {
        int4 q0 = *(const int4*)(edge_data + e);
        int4 q1 = *(const int4*)(edge_data + e + 2);
        int4 q2 = *(const int4*)(edge_data + e + 4);
        int4 q3 = *(const int4*)(edge_data + e + 6);
        unsigned int g0, g1, g2, g3, g4, g5, g6, g7;
        float w0, w1, w2, w3, w4, w5, w6, w7;
        AGG_GATHER(q0, g0, g1, w0, w1, t2);
        AGG_GATHER(q1, g2, g3, w2, w3, t2);
        AGG_GATHER(q2, g4, g5, w4, w5, t2);
        AGG_GATHER(q3, g6, g7, w6, w7, t2);
        aL = fmaf(w0, bflo(g0), aL); aH = fmaf(w0, bfhi(g0), aH);
        aL = fmaf(w1, bflo(g1), aL); aH = fmaf(w1, bfhi(g1), aH);
        aL = fmaf(w2, bflo(g2), aL); aH = fmaf(w2, bfhi(g2), aH);
        aL = fmaf(w3, bflo(g3), aL); aH = fmaf(w3, bfhi(g3), aH);
        aL = fmaf(w4, bflo(g4), aL); aH = fmaf(w4, bfhi(g4), aH);
        aL = fmaf(w5, bflo(g5), aL); aH = fmaf(w5, bfhi(g5), aH);
        aL = fmaf(w6, bflo(g6), aL); aH = fmaf(w6, bfhi(g6), aH);
        aL = fmaf(w7, bflo(g7), aL); aH = fmaf(w7, bfhi(g7), aH);
    }
    unsigned int tn = *(const unsigned int*)(t2 + (size_t)n * 128 + co);
    unsigned int hr = *(const unsigned int*)(hb + (size_t)n * 128 + co);
    float d = dinv[n];
    float2 bb2 = *(const float2*)(b2 + co);
    float oL = fmaxf(fmaf(d, aL + bflo(tn), bb2.x), 0.f) + bflo(hr);
    float oH = fmaxf(fmaf(d, aH + bfhi(tn), bb2.y), 0.f) + bfhi(hr);
    unsigned int packed = (unsigned int)f2bf(oL) | ((unsigned int)f2bf(oH) << 16);
    *(unsigned int*)(out_buf + (size_t)n * 128 + co) = packed;
}

// ---------------------------------------------------------------------------
// pool + FC fused: out[g] = (1/379)*sum_{i,c} out_buf[g*379+i, c]*Wfc[c] + bfc
// 512 threads: lane covers 2 cols (one uint), 8 row groups
// ---------------------------------------------------------------------------
__global__ __launch_bounds__(512) void pool_fc(
    const unsigned short* __restrict__ out_buf, const float* __restrict__ Wfc,
    const float* __restrict__ bfc, float* __restrict__ out)
{
    int g = blockIdx.x;
    int t = threadIdx.x;
    int c2 = (t & 63) * 2, q = t >> 6;
    const unsigned short* p = out_buf + ((size_t)g * NODES + q) * 128 + c2;
    float sL = 0.f, sH = 0.f;
    for (int i = q; i < NODES; i += 8) {
        unsigned int v = *(const unsigned int*)p;
        sL += bflo(v);
        sH += bfhi(v);
        p += 8 * 128;
    }
    float v = sL * Wfc[c2] + sH * Wfc[c2 + 1];
    #pragma unroll
    for (int off = 32; off > 0; off >>= 1) v += __shfl_down(v, off);
    __shared__ float ws8[8];
    if ((t & 63) == 0) ws8[t >> 6] = v;
    __syncthreads();
    if (t == 0) {
        float tot = 0.f;
        #pragma unroll
        for (int k = 0; k < 8; ++k) tot += ws8[k];
        out[g] = tot * (1.0f / (float)NODES) + bfc[0];
    }
}

// ---------------------------------------------------------------------------
extern "C" void kernel_launch(void* const* d_in, const int* in_sizes, int n_in,
                              void* d_out, int out_size, void* d_ws, size_t ws_size,
                              hipStream_t stream)
{
    const float* x   = (const float*)d_in[0];
    const int*   ei  = (const int*)d_in[1];
    const float* ewt = (const float*)d_in[2];
    // d_in[3] = batch (unused; batch[n] == n/379)
    const float* lew = (const float*)d_in[4];
    const float* W1  = (const float*)d_in[5];
    const float* b1  = (const float*)d_in[6];
    const float* W2  = (const float*)d_in[7];
    const float* b2  = (const float*)d_in[8];
    const float* We  = (const float*)d_in[9];
    const float* be  = (const float*)d_in[10];
    const float* Wfc = (const float*)d_in[11];
    const float* bfc = (const float*)d_in[12];
    float* outp = (float*)d_out;

    // workspace layout
    char* p = (char*)d_ws;
    auto alloc = [&](size_t bytes) { void* r = (void*)p; p += (bytes + 255) & ~(size_t)255; return r; };
    int2*  edge_data  = (int2*)alloc((size_t)EPAD2 * 8);
    int*   cnt8       = (int*)alloc((size_t)8 * NN * 4);
    int*   wpos8      = (int*)alloc((size_t)8 * NN * 4);
    int*   rowstart   = (int*)alloc((size_t)(NN + 1) * 4);
    int*   blocksum   = (int*)alloc((size_t)NBLK * 4);
    int*   blockoff   = (int*)alloc((size_t)NBLK * 4);
    float* dinv       = (float*)alloc((size_t)NN * 4);
    unsigned short* WcatT = (unsigned short*)alloc((size_t)256 * KP1 * 2);
    unsigned short* W2T   = (unsigned short*)alloc((size_t)128 * 128 * 2);
    unsigned short* xb    = (unsigned short*)alloc((size_t)NN * KP1 * 2);
    unsigned short* xw1b  = (unsigned short*)alloc((size_t)NN * HID * 2);
    unsigned short* xeb   = (unsigned short*)alloc((size_t)NN * HID * 2);
    unsigned short* hw2b  = (unsigned short*)alloc((size_t)NN * HID * 2);
    unsigned short* out_buf = (unsigned short*)alloc((size_t)NN * HID * 2);
    // alias (disjoint live ranges): xb dead after GEMM1; hb born in aggregate1
    unsigned short* hb = xb;

    // zero histogram + padded CSR (ws is poisoned 0xAA before every launch)
    hipMemsetAsync(cnt8, 0, (size_t)8 * NN * 4, stream);
    hipMemsetAsync(edge_data, 0, (size_t)EPAD2 * 8, stream);

    const int NB = NBLK;                 // 190
    const int EB1024 = EE / 1024;        // 1516

    convert_x<<<(NN * 96 + 255) / 256, 256, 0, stream>>>(x, xb);
    build_wt<<<(256 * KP1 + 128 * 128 + 255) / 256, 256, 0, stream>>>(W1, We, W2, WcatT, W2T);

    edge_hist8<<<EB1024, 256, 0, stream>>>(ei, cnt8);
    scan_rows<<<NB, 256, 0, stream>>>(cnt8, blocksum);
    scan_blocks<<<1, 256, 0, stream>>>(blocksum, blockoff, rowstart);
    scan_write<<<NB, 256, 0, stream>>>(cnt8, blockoff, rowstart, wpos8);
    edge_scatter<<<EB1024, 256, 0, stream>>>(ei, ewt, lew, wpos8, edge_data);
    deg_from_csr<<<NB, 256, 0, stream>>>(rowstart, edge_data, dinv);

    // GEMM1: xw1b = dinv*(xb@W1) bf16 ; xeb = xb@We bf16
    {
        dim3 grid(NN / 128, 2);
        mfma_gemm<<<grid, 256, 0, stream>>>(xb, KP1, WcatT, KP1, xw1b, xeb, dinv, KP1);
    }
    aggregate1_v5<<<NN / 2, 128, 0, stream>>>(xw1b, xeb, rowstart, edge_data,
                                              dinv, b1, be, hb);
    // GEMM2: hw2b = dinv*(hb@W2) bf16
    {
        dim3 grid(NN / 128, 1);
        mfma_gemm<<<grid, 256, 0, stream>>>(hb, 128, W2T, 128, hw2b, nullptr, dinv, 128);
    }
    aggregate2_v5<<<NN / 2, 128, 0, stream>>>(hw2b, rowstart, edge_data,
                                              dinv, b2, hb, out_buf);
    pool_fc<<<NG, 512, 0, stream>>>(out_buf, Wfc, bfc, outp);
}

// Round 10
// 455.291 us; speedup vs baseline: 1.3488x; 1.0163x over previous
//
#include <hip/hip_runtime.h>
#include <hip/hip_bf16.h>

// Problem constants
#define NODES 379
#define NG    128
#define NN    48512          // NODES*NG
#define EE    1552384        // NN*32 ; divisible by 1024
#define EPAD2 (EE + 16 * NN) // CSR slots upper bound (8 subsegs pad2 + row pad8)
#define HID   128
#define INCH  379
#define KP1   384            // INCH padded to multiple of 64
#define NBLK  ((NN + 255) / 256)   // 190 blocks for row-parallel kernels

typedef __bf16 bf16x8 __attribute__((ext_vector_type(8)));
typedef float  f32x4  __attribute__((ext_vector_type(4)));

__device__ __forceinline__ unsigned short f2bf(float f) {
    __hip_bfloat16 b = __float2bfloat16(f);
    return *reinterpret_cast<unsigned short*>(&b);
}
__device__ __forceinline__ float bflo(unsigned int g) {   // low bf16 -> f32
    return __uint_as_float(g << 16);
}
__device__ __forceinline__ float bfhi(unsigned int g) {   // high bf16 -> f32
    return __uint_as_float(g & 0xffff0000u);
}

// ---------------------------------------------------------------------------
// Edge hist: per-XCD-slot dst histogram. Block b covers edges [b*1024,+1024),
// uses private copy cnt8[b&7][*] so atomic lines stay XCD-local.
// ---------------------------------------------------------------------------
__global__ __launch_bounds__(256) void edge_hist8(
    const int* __restrict__ ei, int* __restrict__ cnt8)
{
    int b = blockIdx.x;
    int* cm = cnt8 + (size_t)(b & 7) * NN;
    int e0 = b * 1024 + threadIdx.x * 4;
    int4 d = *(const int4*)(ei + EE + e0);
    atomicAdd(&cm[d.x], 1);
    atomicAdd(&cm[d.y], 1);
    atomicAdd(&cm[d.z], 1);
    atomicAdd(&cm[d.w], 1);
}

// ---------------------------------------------------------------------------
// Parallel 3-phase scan over padded row lengths.
// Row n = 8 subsegs (per XCD slot), each padded to mult of 2; row padded to 8.
// ---------------------------------------------------------------------------
__device__ __forceinline__ int row_len8(const int* cnt8, int n, int* c)
{
    int rowlen = 0;
    #pragma unroll
    for (int x = 0; x < 8; ++x) {
        int v = (n < NN) ? cnt8[(size_t)x * NN + n] : 0;
        c[x] = (v + 1) & ~1;
        rowlen += c[x];
    }
    return (rowlen + 7) & ~7;
}

// Phase 1: per-block sum of row lengths
__global__ __launch_bounds__(256) void scan_rows(
    const int* __restrict__ cnt8, int* __restrict__ blocksum)
{
    int n = blockIdx.x * 256 + threadIdx.x;
    int c[8];
    int rowlen = row_len8(cnt8, n, c);
    #pragma unroll
    for (int off = 32; off > 0; off >>= 1) rowlen += __shfl_down(rowlen, off);
    __shared__ int ws[4];
    if ((threadIdx.x & 63) == 0) ws[threadIdx.x >> 6] = rowlen;
    __syncthreads();
    if (threadIdx.x == 0)
        blocksum[blockIdx.x] = ws[0] + ws[1] + ws[2] + ws[3];
}

// Phase 2: exclusive scan of NBLK block sums (single 256-thread block)
__global__ __launch_bounds__(256) void scan_blocks(
    const int* __restrict__ blocksum, int* __restrict__ blockoff,
    int* __restrict__ rowstart)
{
    int tid = threadIdx.x;
    int lane = tid & 63, wid = tid >> 6;
    int v = (tid < NBLK) ? blocksum[tid] : 0;
    int incl = v;
    #pragma unroll
    for (int off = 1; off < 64; off <<= 1) {
        int t = __shfl_up(incl, off);
        if (lane >= off) incl += t;
    }
    __shared__ int wsum[4], wpre[4];
    if (lane == 63) wsum[wid] = incl;
    __syncthreads();
    if (tid == 0) {
        int acc = 0;
        #pragma unroll
        for (int w = 0; w < 4; ++w) { wpre[w] = acc; acc += wsum[w]; }
        rowstart[NN] = acc;               // grand total
    }
    __syncthreads();
    if (tid < NBLK) blockoff[tid] = wpre[wid] + incl - v;
}

// Phase 3: block-wide scan + write rowstart and the 8 wpos cursors
__global__ __launch_bounds__(256) void scan_write(
    const int* __restrict__ cnt8, const int* __restrict__ blockoff,
    int* __restrict__ rowstart, int* __restrict__ wpos8)
{
    int tid = threadIdx.x;
    int lane = tid & 63, wid = tid >> 6;
    int n = blockIdx.x * 256 + tid;
    int c[8];
    int rowlen = row_len8(cnt8, n, c);
    int incl = rowlen;
    #pragma unroll
    for (int off = 1; off < 64; off <<= 1) {
        int t = __shfl_up(incl, off);
        if (lane >= off) incl += t;
    }
    __shared__ int wsum[4], wpre[4];
    if (lane == 63) wsum[wid] = incl;
    __syncthreads();
    if (tid == 0) {
        int acc = 0;
        #pragma unroll
        for (int w = 0; w < 4; ++w) { wpre[w] = acc; acc += wsum[w]; }
    }
    __syncthreads();
    if (n < NN) {
        int excl = blockoff[blockIdx.x] + wpre[wid] + incl - rowlen;
        rowstart[n] = excl;
        int off = excl;
        #pragma unroll
        for (int x = 0; x < 8; ++x) {
            wpos8[(size_t)x * NN + n] = off;
            off += c[x];
        }
    }
}

// ---------------------------------------------------------------------------
// Edge scatter: effective weight + scatter packed 4B entry
// entry = (bf16(w) << 16) | src   (src < 65536)
// into this block's XCD-slot subsegment of the dst row.
// ---------------------------------------------------------------------------
__global__ __launch_bounds__(256) void edge_scatter(
    const int* __restrict__ ei, const float* __restrict__ ewt,
    const float* __restrict__ lew, int* __restrict__ wpos8,
    unsigned int* __restrict__ edge_data)
{
    int b = blockIdx.x;
    int* wp = wpos8 + (size_t)(b & 7) * NN;
    int e0 = b * 1024 + threadIdx.x * 4;
    int4   s4 = *(const int4*)(ei + e0);
    int4   d4 = *(const int4*)(ei + EE + e0);
    float4 t4 = *(const float4*)(ewt + e0);
    // issue all 4 atomics first; compute sigmoid while they're in flight
    int p0 = atomicAdd(&wp[d4.x], 1);
    int p1 = atomicAdd(&wp[d4.y], 1);
    int p2 = atomicAdd(&wp[d4.z], 1);
    int p3 = atomicAdd(&wp[d4.w], 1);
    int srcs[4] = {s4.x, s4.y, s4.z, s4.w};
    int dsts[4] = {d4.x, d4.y, d4.z, d4.w};
    float ews[4] = {t4.x, t4.y, t4.z, t4.w};
    int pos[4] = {p0, p1, p2, p3};
    #pragma unroll
    for (int u = 0; u < 4; ++u) {
        int li = srcs[u] % NODES, lj = dsts[u] % NODES;
        float s = 0.5f * (lew[li * NODES + lj] + lew[lj * NODES + li]);
        float w = (2.0f / (1.0f + expf(-s))) * ews[u];
        edge_data[pos[u]] = ((unsigned int)f2bf(w) << 16) | (unsigned int)srcs[u];
    }
}

// ---------------------------------------------------------------------------
// deg/dinv from CSR row sums (pads are 0): dinv[n]=rsqrt(sum(bf16 w)+1)
// ---------------------------------------------------------------------------
__global__ __launch_bounds__(256) void deg_from_csr(
    const int* __restrict__ rowstart, const unsigned int* __restrict__ edge_data,
    float* __restrict__ dinv)
{
    int n = blockIdx.x * 256 + threadIdx.x;
    if (n >= NN) return;
    int e0 = rowstart[n], e1 = rowstart[n + 1];
    float s = 0.f;
    for (int e = e0; e < e1; e += 8) {
        uint4 q0 = *(const uint4*)(edge_data + e);
        uint4 q1 = *(const uint4*)(edge_data + e + 4);
        s += (bfhi(q0.x) + bfhi(q0.y)) + (bfhi(q0.z) + bfhi(q0.w))
           + ((bfhi(q1.x) + bfhi(q1.y)) + (bfhi(q1.z) + bfhi(q1.w)));
    }
    dinv[n] = rsqrtf(s + 1.0f);
}

// ---------------------------------------------------------------------------
// x[NN,379] f32 -> xb[NN,384] bf16 (zero-padded K)
// ---------------------------------------------------------------------------
__global__ __launch_bounds__(256) void convert_x(
    const float* __restrict__ x, unsigned short* __restrict__ xb)
{
    int idx = blockIdx.x * 256 + threadIdx.x;
    if (idx >= NN * 96) return;
    int r = idx / 96, kg = (idx % 96) * 4;
    const float* xp = x + (size_t)r * INCH + kg;
    ushort4 o;
    o.x = (kg + 0 < INCH) ? f2bf(xp[0]) : 0;
    o.y = (kg + 1 < INCH) ? f2bf(xp[1]) : 0;
    o.z = (kg + 2 < INCH) ? f2bf(xp[2]) : 0;
    o.w = (kg + 3 < INCH) ? f2bf(xp[3]) : 0;
    *(ushort4*)(xb + (size_t)r * KP1 + kg) = o;
}

// ---------------------------------------------------------------------------
// Weights: WcatT[256][384] bf16 (row n: col n of [W1|We], K zero-padded),
//          W2T[128][128] bf16 (row n: col n of W2)
// ---------------------------------------------------------------------------
__global__ __launch_bounds__(256) void build_wt(
    const float* __restrict__ W1, const float* __restrict__ We,
    const float* __restrict__ W2,
    unsigned short* __restrict__ WcatT, unsigned short* __restrict__ W2T)
{
    int idx = blockIdx.x * 256 + threadIdx.x;
    if (idx < 256 * KP1) {
        int n = idx / KP1, k = idx % KP1;
        float v = 0.f;
        if (k < INCH) v = (n < 128) ? W1[k * 128 + n] : We[k * 128 + (n - 128)];
        WcatT[idx] = f2bf(v);
    } else {
        int i2 = idx - 256 * KP1;
        if (i2 < 128 * 128) {
            int n = i2 / 128, k = i2 % 128;
            W2T[i2] = f2bf(W2[k * 128 + n]);
        }
    }
}

// ---------------------------------------------------------------------------
// bf16 MFMA GEMM: C = A[M,Kp] @ WT[N,Kp]^T, output bf16.
// 128x128 tile, BK=64, 256 thr = 4 waves (2x2 of 64x64 each).
// LDS rows 128 B -> XOR swizzle byte^=(row&7)<<4 on write AND read (G4).
// Output cols 0..127 -> C0 (scaled by dscale[row]), 128..255 -> C1 (unscaled).
// ---------------------------------------------------------------------------
__global__ __launch_bounds__(256) void mfma_gemm(
    const unsigned short* __restrict__ A, int lda,
    const unsigned short* __restrict__ WT, int ldw,
    unsigned short* __restrict__ C0, unsigned short* __restrict__ C1,
    const float* __restrict__ dscale, int Kp)
{
    __shared__ char lds[32 * 1024];
    char* lA = lds;
    char* lB = lds + 16 * 1024;
    int tid = threadIdx.x;
    int lane = tid & 63, wid = tid >> 6;
    int wr = wid >> 1, wc = wid & 1;
    int l16 = lane & 15, lq = lane >> 4;
    size_t bm = (size_t)blockIdx.x * 128;
    int bn = blockIdx.y * 128;
    f32x4 acc[4][4] = {};

    for (int kb = 0; kb < Kp; kb += 64) {
        {   // stage A tile [128 rows][64 k] and B tile [128 cols][64 k]
            int r = tid >> 1, hk = tid & 1;
            const char* ga = (const char*)(A + (bm + r) * (size_t)lda + kb + hk * 32);
            const char* gb = (const char*)(WT + (size_t)(bn + r) * ldw + kb + hk * 32);
            int rs = (r & 7) << 4;
            #pragma unroll
            for (int i = 0; i < 4; ++i) {
                int4 va = *(const int4*)(ga + i * 16);
                *(int4*)(lA + ((r * 128 + hk * 64 + i * 16) ^ rs)) = va;
            }
            #pragma unroll
            for (int i = 0; i < 4; ++i) {
                int4 vb = *(const int4*)(gb + i * 16);
                *(int4*)(lB + ((r * 128 + hk * 64 + i * 16) ^ rs)) = vb;
            }
        }
        __syncthreads();
        #pragma unroll
        for (int ks = 0; ks < 2; ++ks) {
            int kbyte = ks * 64 + lq * 16;
            bf16x8 af[4], bfr[4];
            #pragma unroll
            for (int mi = 0; mi < 4; ++mi) {
                int r = wr * 64 + mi * 16 + l16;
                af[mi] = *(const bf16x8*)(lA + ((r * 128 + kbyte) ^ ((r & 7) << 4)));
            }
            #pragma unroll
            for (int ni = 0; ni < 4; ++ni) {
                int c = wc * 64 + ni * 16 + l16;
                bfr[ni] = *(const bf16x8*)(lB + ((c * 128 + kbyte) ^ ((c & 7) << 4)));
            }
            #pragma unroll
            for (int mi = 0; mi < 4; ++mi)
                #pragma unroll
                for (int ni = 0; ni < 4; ++ni)
                    acc[mi][ni] = __builtin_amdgcn_mfma_f32_16x16x32_bf16(
                        af[mi], bfr[ni], acc[mi][ni], 0, 0, 0);
        }
        __syncthreads();
    }
    // epilogue: C/D layout col=lane&15, row=(lane>>4)*4+reg
    #pragma unroll
    for (int mi = 0; mi < 4; ++mi) {
        size_t rowbase = bm + wr * 64 + mi * 16 + lq * 4;
        float dsc[4];
        #pragma unroll
        for (int j = 0; j < 4; ++j) dsc[j] = dscale[rowbase + j];
        #pragma unroll
        for (int ni = 0; ni < 4; ++ni) {
            int col = bn + wc * 64 + ni * 16 + l16;
            bool toC0 = (col < 128);
            unsigned short* Cb = toC0 ? C0 : C1;
            int cc = toC0 ? col : (col - 128);
            #pragma unroll
            for (int j = 0; j < 4; ++j) {
                float v = acc[mi][ni][j];
                if (toC0) v *= dsc[j];
                Cb[(rowbase + j) * 128 + cc] = f2bf(v);
            }
        }
    }
}

// ---------------------------------------------------------------------------
// Aggregation v6: 1 wave per node (2 nodes per 128-thread block).
// Lane owns 2 adjacent columns via one uint (2xbf16) gather per edge.
// Edge meta = packed 4B: (bf16 w << 16) | src -> uint4 loads give 4 edges.
// Tables pre-scaled by dinv: conv[n] = dinv[n]*(sum ew*T[src] + T[n]) + b
// ---------------------------------------------------------------------------
#define AGG_E(u, TBL)                                                         \
    {                                                                         \
        unsigned int g = *(const unsigned int*)(TBL + (size_t)((u) & 0xFFFFu) * 128 + co); \
        float w = bfhi(u);                                                    \
        aL = fmaf(w, bflo(g), aL);                                            \
        aH = fmaf(w, bfhi(g), aH);                                            \
    }

__global__ __launch_bounds__(128) void aggregate1_v6(
    const unsigned short* __restrict__ t1, const unsigned short* __restrict__ xeb,
    const int* __restrict__ rowstart, const unsigned int* __restrict__ edge_data,
    const float* __restrict__ dinv, const float* __restrict__ b1,
    const float* __restrict__ be, unsigned short* __restrict__ hb)
{
    int lane = threadIdx.x & 63;
    int n = blockIdx.x * 2 + (threadIdx.x >> 6);
    int co = lane << 1;
    int e0 = rowstart[n], e1 = rowstart[n + 1];
    float aL = 0.f, aH = 0.f;
    for (int e = e0; e < e1; e += 8) {
        uint4 qa = *(const uint4*)(edge_data + e);
        uint4 qb = *(const uint4*)(edge_data + e + 4);
        AGG_E(qa.x, t1); AGG_E(qa.y, t1); AGG_E(qa.z, t1); AGG_E(qa.w, t1);
        AGG_E(qb.x, t1); AGG_E(qb.y, t1); AGG_E(qb.z, t1); AGG_E(qb.w, t1);
    }
    unsigned int tn  = *(const unsigned int*)(t1 + (size_t)n * 128 + co);
    unsigned int xen = *(const unsigned int*)(xeb + (size_t)n * 128 + co);
    float d = dinv[n];
    float2 bb1 = *(const float2*)(b1 + co);
    float2 bbe = *(const float2*)(be + co);
    float oL = fmaxf(fmaf(d, aL + bflo(tn), bb1.x), 0.f)
             + fmaxf(bflo(xen) + bbe.x, 0.f);
    float oH = fmaxf(fmaf(d, aH + bfhi(tn), bb1.y), 0.f)
             + fmaxf(bfhi(xen) + bbe.y, 0.f);
    unsigned int packed = (unsigned int)f2bf(oL) | ((unsigned int)f2bf(oH) << 16);
    *(unsigned int*)(hb + (size_t)n * 128 + co) = packed;
}

__global__ __launch_bounds__(128) void aggregate2_v6(
    const unsigned short* __restrict__ t2, const int* __restrict__ rowstart,
    const unsigned int* __restrict__ edge_data,
    const float* __restrict__ dinv, const float* __restrict__ b2,
    const unsigned short* __restrict__ hb, unsigned short* __restrict__ out_buf)
{
    int lane = threadIdx.x & 63;
    int n = blockIdx.x * 2 + (threadIdx.x >> 6);
    int co = lane << 1;
    int e0 = rowstart[n], e1 = rowstart[n + 1];
    float aL = 0.f, aH = 0.f;
    for (int e = e0; e < e1; e += 8) {
        uint4 qa = *(const uint4*)(edge_data + e);
        uint4 qb = *(const uint4*)(edge_data + e + 4);
        AGG_E(qa.x, t2); AGG_E(qa.y, t2); AGG_E(qa.z, t2); AGG_E(qa.w, t2);
        AGG_E(qb.x, t2); AGG_E(qb.y, t2); AGG_E(qb.z, t2); AGG_E(qb.w, t2);
    }
    unsigned int tn = *(const unsigned int*)(t2 + (size_t)n * 128 + co);
    unsigned int hr = *(const unsigned int*)(hb + (size_t)n * 128 + co);
    float d = dinv[n];
    float2 bb2 = *(const float2*)(b2 + co);
    float oL = fmaxf(fmaf(d, aL + bflo(tn), bb2.x), 0.f) + bflo(hr);
    float oH = fmaxf(fmaf(d, aH + bfhi(tn), bb2.y), 0.f) + bfhi(hr);
    unsigned int packed = (unsigned int)f2bf(oL) | ((unsigned int)f2bf(oH) << 16);
    *(unsigned int*)(out_buf + (size_t)n * 128 + co) = packed;
}

// ---------------------------------------------------------------------------
// pool + FC fused: out[g] = (1/379)*sum_{i,c} out_buf[g*379+i, c]*Wfc[c] + bfc
// 512 threads: lane covers 2 cols (one uint), 8 row groups
// ---------------------------------------------------------------------------
__global__ __launch_bounds__(512) void pool_fc(
    const unsigned short* __restrict__ out_buf, const float* __restrict__ Wfc,
    const float* __restrict__ bfc, float* __restrict__ out)
{
    int g = blockIdx.x;
    int t = threadIdx.x;
    int c2 = (t & 63) * 2, q = t >> 6;
    const unsigned short* p = out_buf + ((size_t)g * NODES + q) * 128 + c2;
    float sL = 0.f, sH = 0.f;
    for (int i = q; i < NODES; i += 8) {
        unsigned int v = *(const unsigned int*)p;
        sL += bflo(v);
        sH += bfhi(v);
        p += 8 * 128;
    }
    float v = sL * Wfc[c2] + sH * Wfc[c2 + 1];
    #pragma unroll
    for (int off = 32; off > 0; off >>= 1) v += __shfl_down(v, off);
    __shared__ float ws8[8];
    if ((t & 63) == 0) ws8[t >> 6] = v;
    __syncthreads();
    if (t == 0) {
        float tot = 0.f;
        #pragma unroll
        for (int k = 0; k < 8; ++k) tot += ws8[k];
        out[g] = tot * (1.0f / (float)NODES) + bfc[0];
    }
}

// ---------------------------------------------------------------------------
extern "C" void kernel_launch(void* const* d_in, const int* in_sizes, int n_in,
                              void* d_out, int out_size, void* d_ws, size_t ws_size,
                              hipStream_t stream)
{
    const float* x   = (const float*)d_in[0];
    const int*   ei  = (const int*)d_in[1];
    const float* ewt = (const float*)d_in[2];
    // d_in[3] = batch (unused; batch[n] == n/379)
    const float* lew = (const float*)d_in[4];
    const float* W1  = (const float*)d_in[5];
    const float* b1  = (const float*)d_in[6];
    const float* W2  = (const float*)d_in[7];
    const float* b2  = (const float*)d_in[8];
    const float* We  = (const float*)d_in[9];
    const float* be  = (const float*)d_in[10];
    const float* Wfc = (const float*)d_in[11];
    const float* bfc = (const float*)d_in[12];
    float* outp = (float*)d_out;

    // workspace layout
    char* p = (char*)d_ws;
    auto alloc = [&](size_t bytes) { void* r = (void*)p; p += (bytes + 255) & ~(size_t)255; return r; };
    unsigned int* edge_data = (unsigned int*)alloc((size_t)EPAD2 * 4);
    int*   cnt8       = (int*)alloc((size_t)8 * NN * 4);
    int*   wpos8      = (int*)alloc((size_t)8 * NN * 4);
    int*   rowstart   = (int*)alloc((size_t)(NN + 1) * 4);
    int*   blocksum   = (int*)alloc((size_t)NBLK * 4);
    int*   blockoff   = (int*)alloc((size_t)NBLK * 4);
    float* dinv       = (float*)alloc((size_t)NN * 4);
    unsigned short* WcatT = (unsigned short*)alloc((size_t)256 * KP1 * 2);
    unsigned short* W2T   = (unsigned short*)alloc((size_t)128 * 128 * 2);
    unsigned short* xb    = (unsigned short*)alloc((size_t)NN * KP1 * 2);
    unsigned short* xw1b  = (unsigned short*)alloc((size_t)NN * HID * 2);
    unsigned short* xeb   = (unsigned short*)alloc((size_t)NN * HID * 2);
    unsigned short* hw2b  = (unsigned short*)alloc((size_t)NN * HID * 2);
    unsigned short* out_buf = (unsigned short*)alloc((size_t)NN * HID * 2);
    // alias (disjoint live ranges): xb dead after GEMM1; hb born in aggregate1
    unsigned short* hb = xb;

    // zero histogram + padded CSR (ws is poisoned 0xAA before every launch)
    hipMemsetAsync(cnt8, 0, (size_t)8 * NN * 4, stream);
    hipMemsetAsync(edge_data, 0, (size_t)EPAD2 * 4, stream);

    const int NB = NBLK;                 // 190
    const int EB1024 = EE / 1024;        // 1516

    convert_x<<<(NN * 96 + 255) / 256, 256, 0, stream>>>(x, xb);
    build_wt<<<(256 * KP1 + 128 * 128 + 255) / 256, 256, 0, stream>>>(W1, We, W2, WcatT, W2T);

    edge_hist8<<<EB1024, 256, 0, stream>>>(ei, cnt8);
    scan_rows<<<NB, 256, 0, stream>>>(cnt8, blocksum);
    scan_blocks<<<1, 256, 0, stream>>>(blocksum, blockoff, rowstart);
    scan_write<<<NB, 256, 0, stream>>>(cnt8, blockoff, rowstart, wpos8);
    edge_scatter<<<EB1024, 256, 0, stream>>>(ei, ewt, lew, wpos8, edge_data);
    deg_from_csr<<<NB, 256, 0, stream>>>(rowstart, edge_data, dinv);

    // GEMM1: xw1b = dinv*(xb@W1) bf16 ; xeb = xb@We bf16
    {
        dim3 grid(NN / 128, 2);
        mfma_gemm<<<grid, 256, 0, stream>>>(xb, KP1, WcatT, KP1, xw1b, xeb, dinv, KP1);
    }
    aggregate1_v6<<<NN / 2, 128, 0, stream>>>(xw1b, xeb, rowstart, edge_data,
                                              dinv, b1, be, hb);
    // GEMM2: hw2b = dinv*(hb@W2) bf16
    {
        dim3 grid(NN / 128, 1);
        mfma_gemm<<<grid, 256, 0, stream>>>(hb, 128, W2T, 128, hw2b, nullptr, dinv, 128);
    }
    aggregate2_v6<<<NN / 2, 128, 0, stream>>>(hw2b, rowstart, edge_data,
                                              dinv, b2, hb, out_buf);
    pool_fc<<<NG, 512, 0, stream>>>(out_buf, Wfc, bfc, outp);
}

// Round 12
// 360.607 us; speedup vs baseline: 1.7030x; 1.2626x over previous
//
#include <hip/hip_runtime.h>
#include <hip/hip_bf16.h>

// Problem constants
#define NODES 379
#define NG    128
#define NN    48512          // NODES*NG
#define EE    1552384        // NN*32 ; divisible by 1024
#define HID   128
#define INCH  379
#define KP1   384            // INCH padded to multiple of 64
#define GSTRIDE 14336        // binned-edge slots per graph (mean 12128, +20 sigma)
#define OSTRIDE 8192         // CSR slots per half-graph segment (mean ~6730 padded)
#define NH0   190            // nodes in half 0 (half 1: 189)

typedef __bf16 bf16x8 __attribute__((ext_vector_type(8)));
typedef float  f32x4  __attribute__((ext_vector_type(4)));

__device__ __forceinline__ unsigned short f2bf(float f) {
    __hip_bfloat16 b = __float2bfloat16(f);
    return *reinterpret_cast<unsigned short*>(&b);
}
__device__ __forceinline__ float bflo(unsigned int g) {   // low bf16 -> f32
    return __uint_as_float(g << 16);
}
__device__ __forceinline__ float bfhi(unsigned int g) {   // high bf16 -> f32
    return __uint_as_float(g & 0xffff0000u);
}

// ---------------------------------------------------------------------------
// Edge binning by graph: block = 1024 edges. LDS histogram over 128 graphs,
// one global atomic per (block,graph) reserves a contiguous run -> same-graph
// edges write full 64B lines. Entry = { (dst_local<<16)|src, w as f32 }.
// ---------------------------------------------------------------------------
__global__ __launch_bounds__(256) void edge_bin(
    const int* __restrict__ ei, const float* __restrict__ ewt,
    const float* __restrict__ lew, int* __restrict__ gcur,
    int2* __restrict__ ge64)
{
    __shared__ int lhist[NG];
    __shared__ int lbase[NG];
    int tid = threadIdx.x;
    if (tid < NG) lhist[tid] = 0;
    __syncthreads();
    int e0 = blockIdx.x * 1024 + tid * 4;
    int4   s4 = *(const int4*)(ei + e0);
    int4   d4 = *(const int4*)(ei + EE + e0);
    float4 t4 = *(const float4*)(ewt + e0);
    int   srcs[4] = {s4.x, s4.y, s4.z, s4.w};
    int   dsts[4] = {d4.x, d4.y, d4.z, d4.w};
    float ews[4]  = {t4.x, t4.y, t4.z, t4.w};
    int gg[4], dlo[4], rank[4];
    float wv[4];
    #pragma unroll
    for (int u = 0; u < 4; ++u) {
        gg[u] = dsts[u] / NODES;
        dlo[u] = dsts[u] - gg[u] * NODES;
        rank[u] = atomicAdd(&lhist[gg[u]], 1);
        int li = srcs[u] % NODES;
        float s = 0.5f * (lew[li * NODES + dlo[u]] + lew[dlo[u] * NODES + li]);
        wv[u] = (2.0f / (1.0f + expf(-s))) * ews[u];
    }
    __syncthreads();
    if (tid < NG) lbase[tid] = atomicAdd(&gcur[tid], lhist[tid]);
    __syncthreads();
    #pragma unroll
    for (int u = 0; u < 4; ++u) {
        int pos = lbase[gg[u]] + rank[u];
        if (pos < GSTRIDE)
            ge64[(size_t)gg[u] * GSTRIDE + pos] =
                make_int2((dlo[u] << 16) | srcs[u], __float_as_int(wv[u]));
    }
}

// ---------------------------------------------------------------------------
// Per-half-graph CSR build: block = (graph g, half). Reads g's binned segment
// sequentially, LDS histogram over its nodes, scan, LDS scatter (rows padded
// to 8 with zero entries), f32 deg accumulation, then fully-coalesced global
// write of the CSR segment + rowse (start,end) + dinv.
// ---------------------------------------------------------------------------
__global__ __launch_bounds__(512) void build_csr(
    const int2* __restrict__ ge64, const int* __restrict__ gcur,
    unsigned int* __restrict__ edge_data, int2* __restrict__ rowse,
    float* __restrict__ dinv)
{
    __shared__ int hist[192];
    __shared__ int pref[192];
    __shared__ int curs[192];
    __shared__ float degs[192];
    __shared__ unsigned int buf[OSTRIDE];
    int tid = threadIdx.x;
    int g = blockIdx.x >> 1, half = blockIdx.x & 1;
    int lo = half ? NH0 : 0;
    int NH = half ? (NODES - NH0) : NH0;
    int cnt = gcur[g];
    if (cnt > GSTRIDE) cnt = GSTRIDE;
    if (tid < 192) { hist[tid] = 0; degs[tid] = 0.f; }
    __syncthreads();
    const int2* gsrc = ge64 + (size_t)g * GSTRIDE;
    for (int i = tid; i < cnt; i += 512) {
        int r = (gsrc[i].x >> 16) - lo;
        if (r >= 0 && r < NH) atomicAdd(&hist[r], 1);
    }
    __syncthreads();
    // inclusive Hillis-Steele scan of padded row lengths over 192 slots
    if (tid < 192) pref[tid] = (tid < NH) ? ((hist[tid] + 7) & ~7) : 0;
    __syncthreads();
    for (int off = 1; off < 192; off <<= 1) {
        int v = 0;
        if (tid < 192 && tid >= off) v = pref[tid - off];
        __syncthreads();
        if (tid < 192) pref[tid] += v;
        __syncthreads();
    }
    int segbase = blockIdx.x * OSTRIDE;
    int ptot = pref[191];
    if (ptot > OSTRIDE) ptot = OSTRIDE;    // safety (impossible for this input)
    if (tid < NH) {
        int plen = (hist[tid] + 7) & ~7;
        int excl = pref[tid] - plen;
        curs[tid] = excl;
        rowse[(size_t)g * NODES + lo + tid] =
            make_int2(segbase + excl, segbase + excl + plen);
    }
    for (int j = tid; j < ptot; j += 512) buf[j] = 0;
    __syncthreads();
    for (int i = tid; i < cnt; i += 512) {
        int2 e = gsrc[i];
        int r = (e.x >> 16) - lo;
        if (r >= 0 && r < NH) {
            float w = __int_as_float(e.y);
            int p = atomicAdd(&curs[r], 1);
            if (p < OSTRIDE)
                buf[p] = ((unsigned int)f2bf(w) << 16) | (unsigned int)(e.x & 0xFFFF);
            atomicAdd(&degs[r], w);
        }
    }
    __syncthreads();
    for (int j = tid; j < ptot; j += 512)
        edge_data[segbase + j] = buf[j];
    if (tid < NH)
        dinv[(size_t)g * NODES + lo + tid] = rsqrtf(degs[tid] + 1.0f);
}

// ---------------------------------------------------------------------------
// x[NN,379] f32 -> xb[NN,384] bf16 (zero-padded K)
// ---------------------------------------------------------------------------
__global__ __launch_bounds__(256) void convert_x(
    const float* __restrict__ x, unsigned short* __restrict__ xb)
{
    int idx = blockIdx.x * 256 + threadIdx.x;
    if (idx >= NN * 96) return;
    int r = idx / 96, kg = (idx % 96) * 4;
    const float* xp = x + (size_t)r * INCH + kg;
    ushort4 o;
    o.x = (kg + 0 < INCH) ? f2bf(xp[0]) : 0;
    o.y = (kg + 1 < INCH) ? f2bf(xp[1]) : 0;
    o.z = (kg + 2 < INCH) ? f2bf(xp[2]) : 0;
    o.w = (kg + 3 < INCH) ? f2bf(xp[3]) : 0;
    *(ushort4*)(xb + (size_t)r * KP1 + kg) = o;
}

// ---------------------------------------------------------------------------
// Weights: WcatT[256][384] bf16 (row n: col n of [W1|We], K zero-padded),
//          W2T[128][128] bf16 (row n: col n of W2)
// ---------------------------------------------------------------------------
__global__ __launch_bounds__(256) void build_wt(
    const float* __restrict__ W1, const float* __restrict__ We,
    const float* __restrict__ W2,
    unsigned short* __restrict__ WcatT, unsigned short* __restrict__ W2T)
{
    int idx = blockIdx.x * 256 + threadIdx.x;
    if (idx < 256 * KP1) {
        int n = idx / KP1, k = idx % KP1;
        float v = 0.f;
        if (k < INCH) v = (n < 128) ? W1[k * 128 + n] : We[k * 128 + (n - 128)];
        WcatT[idx] = f2bf(v);
    } else {
        int i2 = idx - 256 * KP1;
        if (i2 < 128 * 128) {
            int n = i2 / 128, k = i2 % 128;
            W2T[i2] = f2bf(W2[k * 128 + n]);
        }
    }
}

// ---------------------------------------------------------------------------
// bf16 MFMA GEMM: C = A[M,Kp] @ WT[N,Kp]^T, output bf16.
// 128x128 tile, BK=64, 256 thr = 4 waves (2x2 of 64x64 each).
// LDS rows 128 B -> XOR swizzle byte^=(row&7)<<4 on write AND read (G4).
// Output cols 0..127 -> C0 (scaled by dscale[row]), 128..255 -> C1 (unscaled).
// ---------------------------------------------------------------------------
__global__ __launch_bounds__(256) void mfma_gemm(
    const unsigned short* __restrict__ A, int lda,
    const unsigned short* __restrict__ WT, int ldw,
    unsigned short* __restrict__ C0, unsigned short* __restrict__ C1,
    const float* __restrict__ dscale, int Kp)
{
    __shared__ char lds[32 * 1024];
    char* lA = lds;
    char* lB = lds + 16 * 1024;
    int tid = threadIdx.x;
    int lane = tid & 63, wid = tid >> 6;
    int wr = wid >> 1, wc = wid & 1;
    int l16 = lane & 15, lq = lane >> 4;
    size_t bm = (size_t)blockIdx.x * 128;
    int bn = blockIdx.y * 128;
    f32x4 acc[4][4] = {};

    for (int kb = 0; kb < Kp; kb += 64) {
        {   // stage A tile [128 rows][64 k] and B tile [128 cols][64 k]
            int r = tid >> 1, hk = tid & 1;
            const char* ga = (const char*)(A + (bm + r) * (size_t)lda + kb + hk * 32);
            const char* gb = (const char*)(WT + (size_t)(bn + r) * ldw + kb + hk * 32);
            int rs = (r & 7) << 4;
            #pragma unroll
            for (int i = 0; i < 4; ++i) {
                int4 va = *(const int4*)(ga + i * 16);
                *(int4*)(lA + ((r * 128 + hk * 64 + i * 16) ^ rs)) = va;
            }
            #pragma unroll
            for (int i = 0; i < 4; ++i) {
                int4 vb = *(const int4*)(gb + i * 16);
                *(int4*)(lB + ((r * 128 + hk * 64 + i * 16) ^ rs)) = vb;
            }
        }
        __syncthreads();
        #pragma unroll
        for (int ks = 0; ks < 2; ++ks) {
            int kbyte = ks * 64 + lq * 16;
            bf16x8 af[4], bfr[4];
            #pragma unroll
            for (int mi = 0; mi < 4; ++mi) {
                int r = wr * 64 + mi * 16 + l16;
                af[mi] = *(const bf16x8*)(lA + ((r * 128 + kbyte) ^ ((r & 7) << 4)));
            }
            #pragma unroll
            for (int ni = 0; ni < 4; ++ni) {
                int c = wc * 64 + ni * 16 + l16;
                bfr[ni] = *(const bf16x8*)(lB + ((c * 128 + kbyte) ^ ((c & 7) << 4)));
            }
            #pragma unroll
            for (int mi = 0; mi < 4; ++mi)
                #pragma unroll
                for (int ni = 0; ni < 4; ++ni)
                    acc[mi][ni] = __builtin_amdgcn_mfma_f32_16x16x32_bf16(
                        af[mi], bfr[ni], acc[mi][ni], 0, 0, 0);
        }
        __syncthreads();
    }
    // epilogue: C/D layout col=lane&15, row=(lane>>4)*4+reg
    #pragma unroll
    for (int mi = 0; mi < 4; ++mi) {
        size_t rowbase = bm + wr * 64 + mi * 16 + lq * 4;
        float dsc[4];
        #pragma unroll
        for (int j = 0; j < 4; ++j) dsc[j] = dscale[rowbase + j];
        #pragma unroll
        for (int ni = 0; ni < 4; ++ni) {
            int col = bn + wc * 64 + ni * 16 + l16;
            bool toC0 = (col < 128);
            unsigned short* Cb = toC0 ? C0 : C1;
            int cc = toC0 ? col : (col - 128);
            #pragma unroll
            for (int j = 0; j < 4; ++j) {
                float v = acc[mi][ni][j];
                if (toC0) v *= dsc[j];
                Cb[(rowbase + j) * 128 + cc] = f2bf(v);
            }
        }
    }
}

// ---------------------------------------------------------------------------
// Aggregation v7: 1 wave per node (2 nodes per 128-thread block).
// Lane owns 2 adjacent columns via one uint (2xbf16) gather per edge.
// Edge meta = packed 4B: (bf16 w << 16) | src -> uint4 loads give 4 edges.
// Row bounds come from rowse[n] = (start, end); rows padded to 8 with zeros.
// Tables pre-scaled by dinv: conv[n] = dinv[n]*(sum ew*T[src] + T[n]) + b
// ---------------------------------------------------------------------------
#define AGG_E(u, TBL)                                                         \
    {                                                                         \
        unsigned int g = *(const unsigned int*)(TBL + (size_t)((u) & 0xFFFFu) * 128 + co); \
        float w = bfhi(u);                                                    \
        aL = fmaf(w, bflo(g), aL);                                            \
        aH = fmaf(w, bfhi(g), aH);                                            \
    }

__global__ __launch_bounds__(128) void aggregate1_v7(
    const unsigned short* __restrict__ t1, const unsigned short* __restrict__ xeb,
    const int2* __restrict__ rowse, const unsigned int* __restrict__ edge_data,
    const float* __restrict__ dinv, const float* __restrict__ b1,
    const float* __restrict__ be, unsigned short* __restrict__ hb)
{
    int lane = threadIdx.x & 63;
    int n = blockIdx.x * 2 + (threadIdx.x >> 6);
    int co = lane << 1;
    int2 se = rowse[n];
    int e0 = se.x, e1 = se.y;
    float aL = 0.f, aH = 0.f;
    for (int e = e0; e < e1; e += 8) {
        uint4 qa = *(const uint4*)(edge_data + e);
        uint4 qb = *(const uint4*)(edge_data + e + 4);
        AGG_E(qa.x, t1); AGG_E(qa.y, t1); AGG_E(qa.z, t1); AGG_E(qa.w, t1);
        AGG_E(qb.x, t1); AGG_E(qb.y, t1); AGG_E(qb.z, t1); AGG_E(qb.w, t1);
    }
    unsigned int tn  = *(const unsigned int*)(t1 + (size_t)n * 128 + co);
    unsigned int xen = *(const unsigned int*)(xeb + (size_t)n * 128 + co);
    float d = dinv[n];
    float2 bb1 = *(const float2*)(b1 + co);
    float2 bbe = *(const float2*)(be + co);
    float oL = fmaxf(fmaf(d, aL + bflo(tn), bb1.x), 0.f)
             + fmaxf(bflo(xen) + bbe.x, 0.f);
    float oH = fmaxf(fmaf(d, aH + bfhi(tn), bb1.y), 0.f)
             + fmaxf(bfhi(xen) + bbe.y, 0.f);
    unsigned int packed = (unsigned int)f2bf(oL) | ((unsigned int)f2bf(oH) << 16);
    *(unsigned int*)(hb + (size_t)n * 128 + co) = packed;
}

__global__ __launch_bounds__(128) void aggregate2_v7(
    const unsigned short* __restrict__ t2, const int2* __restrict__ rowse,
    const unsigned int* __restrict__ edge_data,
    const float* __restrict__ dinv, const float* __restrict__ b2,
    const unsigned short* __restrict__ hb, unsigned short* __restrict__ out_buf)
{
    int lane = threadIdx.x & 63;
    int n = blockIdx.x * 2 + (threadIdx.x >> 6);
    int co = lane << 1;
    int2 se = rowse[n];
    int e0 = se.x, e1 = se.y;
    float aL = 0.f, aH = 0.f;
    for (int e = e0; e < e1; e += 8) {
        uint4 qa = *(const uint4*)(edge_data + e);
        uint4 qb = *(const uint4*)(edge_data + e + 4);
        AGG_E(qa.x, t2); AGG_E(qa.y, t2); AGG_E(qa.z, t2); AGG_E(qa.w, t2);
        AGG_E(qb.x, t2); AGG_E(qb.y, t2); AGG_E(qb.z, t2); AGG_E(qb.w, t2);
    }
    unsigned int tn = *(const unsigned int*)(t2 + (size_t)n * 128 + co);
    unsigned int hr = *(const unsigned int*)(hb + (size_t)n * 128 + co);
    float d = dinv[n];
    float2 bb2 = *(const float2*)(b2 + co);
    float oL = fmaxf(fmaf(d, aL + bflo(tn), bb2.x), 0.f) + bflo(hr);
    float oH = fmaxf(fmaf(d, aH + bfhi(tn), bb2.y), 0.f) + bfhi(hr);
    unsigned int packed = (unsigned int)f2bf(oL) | ((unsigned int)f2bf(oH) << 16);
    *(unsigned int*)(out_buf + (size_t)n * 128 + co) = packed;
}

// ---------------------------------------------------------------------------
// pool + FC fused: out[g] = (1/379)*sum_{i,c} out_buf[g*379+i, c]*Wfc[c] + bfc
// 512 threads: lane covers 2 cols (one uint), 8 row groups
// ---------------------------------------------------------------------------
__global__ __launch_bounds__(512) void pool_fc(
    const unsigned short* __restrict__ out_buf, const float* __restrict__ Wfc,
    const float* __restrict__ bfc, float* __restrict__ out)
{
    int g = blockIdx.x;
    int t = threadIdx.x;
    int c2 = (t & 63) * 2, q = t >> 6;
    const unsigned short* p = out_buf + ((size_t)g * NODES + q) * 128 + c2;
    float sL = 0.f, sH = 0.f;
    for (int i = q; i < NODES; i += 8) {
        unsigned int v = *(const unsigned int*)p;
        sL += bflo(v);
        sH += bfhi(v);
        p += 8 * 128;
    }
    float v = sL * Wfc[c2] + sH * Wfc[c2 + 1];
    #pragma unroll
    for (int off = 32; off > 0; off >>= 1) v += __shfl_down(v, off);
    __shared__ float ws8[8];
    if ((t & 63) == 0) ws8[t >> 6] = v;
    __syncthreads();
    if (t == 0) {
        float tot = 0.f;
        #pragma unroll
        for (int k = 0; k < 8; ++k) tot += ws8[k];
        out[g] = tot * (1.0f / (float)NODES) + bfc[0];
    }
}

// ---------------------------------------------------------------------------
extern "C" void kernel_launch(void* const* d_in, const int* in_sizes, int n_in,
                              void* d_out, int out_size, void* d_ws, size_t ws_size,
                              hipStream_t stream)
{
    const float* x   = (const float*)d_in[0];
    const int*   ei  = (const int*)d_in[1];
    const float* ewt = (const float*)d_in[2];
    // d_in[3] = batch (unused; batch[n] == n/379)
    const float* lew = (const float*)d_in[4];
    const float* W1  = (const float*)d_in[5];
    const float* b1  = (const float*)d_in[6];
    const float* W2  = (const float*)d_in[7];
    const float* b2  = (const float*)d_in[8];
    const float* We  = (const float*)d_in[9];
    const float* be  = (const float*)d_in[10];
    const float* Wfc = (const float*)d_in[11];
    const float* bfc = (const float*)d_in[12];
    float* outp = (float*)d_out;

    // workspace layout
    char* p = (char*)d_ws;
    auto alloc = [&](size_t bytes) { void* r = (void*)p; p += (bytes + 255) & ~(size_t)255; return r; };
    int2*  ge64       = (int2*)alloc((size_t)NG * GSTRIDE * 8);         // 14.7 MB
    unsigned int* edge_data = (unsigned int*)alloc((size_t)NG * 2 * OSTRIDE * 4); // 8.4 MB
    int*   gcur       = (int*)alloc((size_t)NG * 4);
    int2*  rowse      = (int2*)alloc((size_t)NN * 8);
    float* dinv       = (float*)alloc((size_t)NN * 4);
    unsigned short* WcatT = (unsigned short*)alloc((size_t)256 * KP1 * 2);
    unsigned short* W2T   = (unsigned short*)alloc((size_t)128 * 128 * 2);
    unsigned short* xb    = (unsigned short*)alloc((size_t)NN * KP1 * 2);
    unsigned short* xw1b  = (unsigned short*)alloc((size_t)NN * HID * 2);
    unsigned short* xeb   = (unsigned short*)alloc((size_t)NN * HID * 2);
    unsigned short* hw2b  = (unsigned short*)alloc((size_t)NN * HID * 2);
    unsigned short* out_buf = (unsigned short*)alloc((size_t)NN * HID * 2);
    // alias (disjoint live ranges): xb dead after GEMM1; hb born in aggregate1
    unsigned short* hb = xb;

    // only per-graph cursors need zeroing (512 B)
    hipMemsetAsync(gcur, 0, (size_t)NG * 4, stream);

    const int EB1024 = EE / 1024;        // 1516

    convert_x<<<(NN * 96 + 255) / 256, 256, 0, stream>>>(x, xb);
    build_wt<<<(256 * KP1 + 128 * 128 + 255) / 256, 256, 0, stream>>>(W1, We, W2, WcatT, W2T);

    edge_bin<<<EB1024, 256, 0, stream>>>(ei, ewt, lew, gcur, ge64);
    build_csr<<<NG * 2, 512, 0, stream>>>(ge64, gcur, edge_data, rowse, dinv);

    // GEMM1: xw1b = dinv*(xb@W1) bf16 ; xeb = xb@We bf16
    {
        dim3 grid(NN / 128, 2);
        mfma_gemm<<<grid, 256, 0, stream>>>(xb, KP1, WcatT, KP1, xw1b, xeb, dinv, KP1);
    }
    aggregate1_v7<<<NN / 2, 128, 0, stream>>>(xw1b, xeb, rowse, edge_data,
                                              dinv, b1, be, hb);
    // GEMM2: hw2b = dinv*(hb@W2) bf16
    {
        dim3 grid(NN / 128, 1);
        mfma_gemm<<<grid, 256, 0, stream>>>(hb, 128, W2T, 128, hw2b, nullptr, dinv, 128);
    }
    aggregate2_v7<<<NN / 2, 128, 0, stream>>>(hw2b, rowse, edge_data,
                                              dinv, b2, hb, out_buf);
    pool_fc<<<NG, 512, 0, stream>>>(out_buf, Wfc, bfc, outp);
}